// Round 5
// baseline (8027.652 us; speedup 1.0000x reference)
//
#include <hip/hip_runtime.h>

#define NN 8192
#define DD 32
// stagger-padded LDS index: +4 floats of pad per 16 (keeps 16B alignment)
#define SIDX(c) ((c) + 4 * ((c) >> 4))

constexpr float kEps   = 0.1f;
constexpr float kStab  = 1e-8f;
constexpr float kMass  = 1.0f / 8192.0f;     // mu = nu = 1/n
constexpr float kInvSc = 1.0f / 256.0f;      // K stored as fp8 of 256*K
constexpr float kLnSc  = 5.545177444479562f; // ln(256)

// small-buffer regions (floats), after the 3*64MB K8 block:
// 0:u_st 1:vbuf 2:rawst0 3:rawst1 4..7:SV[p][zz] 8..11:SU[p][zz]
#define OFF_U     0
#define OFF_VBUF  (1 * NN)
#define OFF_RAWST (2 * NN)
#define OFF_SV    (4 * NN)
#define OFF_SU    (8 * NN)

typedef float v2f __attribute__((ext_vector_type(2)));

__device__ inline void cvt8x4(unsigned int w, float* out) {
    v2f lo = __builtin_amdgcn_cvt_pk_f32_fp8(w, false);
    v2f hi = __builtin_amdgcn_cvt_pk_f32_fp8(w, true);
    out[0] = lo.x; out[1] = lo.y; out[2] = hi.x; out[3] = hi.y;
}
__device__ inline void cvt16(uint4 kk, float* f) {
    cvt8x4(kk.x, f); cvt8x4(kk.y, f + 4); cvt8x4(kk.z, f + 8); cvt8x4(kk.w, f + 12);
}
__device__ inline unsigned int pack8x4(float a, float b, float c, float d) {
    int v = 0;
    v = __builtin_amdgcn_cvt_pk_fp8_f32(a, b, v, false);
    v = __builtin_amdgcn_cvt_pk_fp8_f32(c, d, v, true);
    return (unsigned int)v;
}
__device__ inline float xform(float raw) {
    return kMass * __builtin_amdgcn_rcpf(fmaf(raw, kInvSc, kStab));
}

// ------------------------------------------------- init small buffers
// regions 10,11 (SU[1][*]) = rstar so xform(rstar)=1 (u0=1); region 0 = 1.0
__global__ void sk_init(float* __restrict__ small, double* __restrict__ wacc) {
    const int idx = blockIdx.x * 256 + threadIdx.x;   // grid 384 -> 12*NN
    const int region = idx >> 13;
    float val = 0.0f;
    if (region == 0) val = 1.0f;
    else if (region >= 10) val = (kMass - kStab) * 256.0f;
    small[idx] = val;
    if (idx < 6) ((unsigned int*)wacc)[idx] = 0u;
}

// -------------------------------- build K8 = fp8(256*exp(-cost/eps)), z = transport
__global__ __launch_bounds__(256) void sk_build_k(const float* __restrict__ src,
                                                  const float* __restrict__ tgt,
                                                  unsigned char* __restrict__ K8) {
    const int z = blockIdx.z;
    const float* X = src; const float* Y = tgt;
    if (z == 1) Y = src; else if (z == 2) X = tgt;
    unsigned char* K = K8 + (size_t)z * NN * NN;

    __shared__ float xs[DD * 64];
    __shared__ float ys[DD * 64];
    __shared__ float sx[64], sy[64];
    const int t  = threadIdx.x;
    const int r0 = blockIdx.y * 64, c0 = blockIdx.x * 64;

    for (int idx = t; idx < DD * 64; idx += 256) {
        int d = idx >> 6, row = idx & 63;
        xs[idx] = X[(size_t)(r0 + row) * DD + d];
        ys[idx] = Y[(size_t)(c0 + row) * DD + d];
    }
    __syncthreads();
    if (t < 64) {
        float s = 0.f;
        for (int d = 0; d < DD; d++) { float v = xs[d * 64 + t]; s = fmaf(v, v, s); }
        sx[t] = s;
    } else if (t < 128) {
        int q = t - 64; float s = 0.f;
        for (int d = 0; d < DD; d++) { float v = ys[d * 64 + q]; s = fmaf(v, v, s); }
        sy[q] = s;
    }
    __syncthreads();

    const int tr = t >> 4, tc = t & 15;
    float acc[4][4] = {};
    for (int d = 0; d < DD; d++) {
        const float4 xa = *reinterpret_cast<const float4*>(&xs[d * 64 + 4 * tr]);
        const float4 yb = *reinterpret_cast<const float4*>(&ys[d * 64 + 4 * tc]);
        const float xav[4] = {xa.x, xa.y, xa.z, xa.w};
        const float ybv[4] = {yb.x, yb.y, yb.z, yb.w};
#pragma unroll
        for (int a = 0; a < 4; a++)
#pragma unroll
            for (int b = 0; b < 4; b++) acc[a][b] = fmaf(xav[a], ybv[b], acc[a][b]);
    }
#pragma unroll
    for (int a = 0; a < 4; a++) {
        const int r = r0 + 4 * tr + a;
        const float sxa = sx[4 * tr + a];
        float e[4];
#pragma unroll
        for (int b = 0; b < 4; b++) {
            float cost = sxa + sy[4 * tc + b] - 2.0f * acc[a][b];
            cost = fmaxf(cost, 0.0f);
            e[b] = __expf(fmaf(-10.0f, cost, kLnSc));   // 256 * exp(-cost/eps)
        }
        *reinterpret_cast<unsigned int*>(&K[(size_t)r * NN + c0 + 4 * tc]) =
            pack8x4(e[0], e[1], e[2], e[3]);
    }
}

// -------------------------------- symmetric matvec tile: y += K x (upper triangle)
// One 256x256 tile per block; off-diag tiles add both T*xC (rows) and T^T*xR (cols).
__device__ inline void symv_tile(const unsigned char* __restrict__ K,
                                 const float* __restrict__ xraw,
                                 float* __restrict__ y,
                                 float* __restrict__ zslice,
                                 float* __restrict__ smem, int f) {
    const int t = threadIdx.x;
    int R = (int)(0.5f * (65.0f - sqrtf(4225.0f - 8.0f * (float)f)));
    while (R * (65 - R) / 2 > f) --R;
    while ((R + 1) * (64 - R) / 2 <= f) ++R;
    const int C = R + (f - R * (65 - R) / 2);
    const bool offdiag = (R != C);

    float* xCs  = smem;         // 320
    float* xRs  = smem + 320;   // 256
    float* cred = smem + 576;   // 16 x 320

    xCs[SIDX(t)] = xform(xraw[C * 256 + t]);
    xRs[t]       = xform(xraw[R * 256 + t]);
    if (t < 16) {
        const int j = f * 16 + t;
        if (j < NN) zslice[j] = 0.0f;
    }
    __syncthreads();

    const int lane = t & 63, w = t >> 6, g = lane >> 4, i = lane & 15;
    float xc[16];
#pragma unroll
    for (int q = 0; q < 4; q++) {
        float4 v4 = *reinterpret_cast<const float4*>(&xCs[20 * i + 4 * q]);
        xc[4 * q] = v4.x; xc[4 * q + 1] = v4.y; xc[4 * q + 2] = v4.z; xc[4 * q + 3] = v4.w;
    }
    float cacc[16] = {};
    const unsigned char* Tp = K + (size_t)(R * 256) * NN + C * 256 + 16 * i;
    float* yR = y + R * 256;
#pragma unroll 4
    for (int s = 0; s < 16; s++) {
        const int row = 64 * w + 4 * s + g;
        uint4 kk = *reinterpret_cast<const uint4*>(Tp + (size_t)row * NN);
        const float xr = xRs[row];
        float fv[16];
        cvt16(kk, fv);
        float rs = 0.f;
#pragma unroll
        for (int k = 0; k < 16; k++) rs = fmaf(fv[k], xc[k], rs);
        if (offdiag) {
#pragma unroll
            for (int k = 0; k < 16; k++) cacc[k] = fmaf(fv[k], xr, cacc[k]);
        }
        rs += __shfl_down(rs, 8);
        rs += __shfl_down(rs, 4);
        rs += __shfl_down(rs, 2);
        rs += __shfl_down(rs, 1);
        if (i == 0) atomicAdd(&yR[row], rs);
    }
    if (offdiag) {
        const int pidx = w * 4 + g;
        float* cw = &cred[pidx * 320 + 20 * i];
#pragma unroll
        for (int q = 0; q < 4; q++) {
            float4 v4 = {cacc[4 * q], cacc[4 * q + 1], cacc[4 * q + 2], cacc[4 * q + 3]};
            *reinterpret_cast<float4*>(cw + 4 * q) = v4;
        }
        __syncthreads();
        float s = 0.f;
#pragma unroll
        for (int p = 0; p < 16; p++) s += cred[p * 320 + SIDX(t)];
        atomicAdd(&y[C * 256 + t], s);
    }
}

// -------------------------------- phase1: st colsum (z=0) + ss/tt symv(u) (z=1,2)
__global__ __launch_bounds__(256) void sk_phase1(const unsigned char* __restrict__ K8,
                                                 float* __restrict__ small, int it) {
    __shared__ float smem[5696];
    const int z = blockIdx.z;
    const int t = threadIdx.x;
    const int p = it & 1, q = (it + 1) & 1;

    if (z == 0) {
        const int b = blockIdx.x;
        if (b >= 512) return;
        float* us  = smem;        // 128
        float* red = smem + 128;  // 4 x 1280
        const int lane = t & 63, w = t >> 6;
        const int c0 = (b & 7) * 1024, r0 = (b >> 3) * 128;
        const unsigned char* K = K8;
        float* rc_out = small + OFF_RAWST + p * NN;
        if (t < 128) us[t] = small[OFF_U + r0 + t];
        __syncthreads();

        float acc[16] = {};
        const unsigned char* kp = K + (size_t)(r0 + 32 * w) * NN + c0 + 16 * lane;
        for (int i = 0; i < 32; i += 4) {
            uint4 k0 = *reinterpret_cast<const uint4*>(kp);
            uint4 k1 = *reinterpret_cast<const uint4*>(kp + (size_t)NN);
            uint4 k2 = *reinterpret_cast<const uint4*>(kp + (size_t)2 * NN);
            uint4 k3 = *reinterpret_cast<const uint4*>(kp + (size_t)3 * NN);
            kp += (size_t)4 * NN;
            const float u0 = us[32 * w + i + 0], u1 = us[32 * w + i + 1];
            const float u2 = us[32 * w + i + 2], u3 = us[32 * w + i + 3];
            float f[16];
            cvt16(k0, f);
#pragma unroll
            for (int j = 0; j < 16; j++) acc[j] = fmaf(f[j], u0, acc[j]);
            cvt16(k1, f);
#pragma unroll
            for (int j = 0; j < 16; j++) acc[j] = fmaf(f[j], u1, acc[j]);
            cvt16(k2, f);
#pragma unroll
            for (int j = 0; j < 16; j++) acc[j] = fmaf(f[j], u2, acc[j]);
            cvt16(k3, f);
#pragma unroll
            for (int j = 0; j < 16; j++) acc[j] = fmaf(f[j], u3, acc[j]);
        }
        float* rw = &red[w * 1280 + 20 * lane];
#pragma unroll
        for (int g = 0; g < 4; g++) {
            float4 v = {acc[4 * g], acc[4 * g + 1], acc[4 * g + 2], acc[4 * g + 3]};
            *reinterpret_cast<float4*>(rw + 4 * g) = v;
        }
        __syncthreads();
        for (int c = t; c < 1024; c += 256) {
            const int sc = SIDX(c);
            const float s = red[sc] + red[1280 + sc] + red[2560 + sc] + red[3840 + sc];
            atomicAdd(&rc_out[c0 + c], s);
        }
    } else {
        const int zz = z - 1;
        const unsigned char* K = K8 + (size_t)z * NN * NN;
        const float* xraw = small + OFF_SU + q * 2 * NN + zz * NN;  // SU[(it-1)&1]
        float* yout = small + OFF_SV + p * 2 * NN + zz * NN;
        float* zbuf = small + OFF_SV + q * 2 * NN + zz * NN;
        symv_tile(K, xraw, yout, zbuf, smem, blockIdx.x);
    }
}

// -------------------------------- phase2: st rowsum (z=0) + ss/tt symv(v) (z=1,2)
__global__ __launch_bounds__(256) void sk_phase2(const unsigned char* __restrict__ K8,
                                                 float* __restrict__ small, int it) {
    __shared__ float smem[10240];
    const int z = blockIdx.z;
    const int t = threadIdx.x;
    const int p = it & 1, q = (it + 1) & 1;

    if (z == 0) {
        const int b = blockIdx.x;
        if (b >= 256) return;
        float* vs = smem;
        const unsigned char* K = K8;
        const float* rc = small + OFF_RAWST + p * NN;
        float* rc_zero = small + OFF_RAWST + q * NN;
        float* vbuf = small + OFF_VBUF;
        float* u_arr = small + OFF_U;

#pragma unroll
        for (int qq = 0; qq < 8; qq++) {
            const int j = 4 * t + 1024 * qq;
            float4 r = *reinterpret_cast<const float4*>(rc + j);
            float4 g;
            g.x = xform(r.x); g.y = xform(r.y); g.z = xform(r.z); g.w = xform(r.w);
            *reinterpret_cast<float4*>(&vs[SIDX(j)]) = g;
            if ((j >> 5) == b) *reinterpret_cast<float4*>(&vbuf[j]) = g;
        }
        if (t < 32) rc_zero[b * 32 + t] = 0.0f;
        __syncthreads();

        const int lane = t & 63, w = t >> 6;
        const int rbase = b * 32 + 8 * w;
        float acc[8] = {};
        const unsigned char* rp = K + (size_t)rbase * NN + 16 * lane;
        for (int s = 0; s < 8; s++) {
            const float* vp = &vs[20 * lane + 1280 * s];
            const float4 va = *reinterpret_cast<const float4*>(vp);
            const float4 vb = *reinterpret_cast<const float4*>(vp + 4);
            const float4 vc = *reinterpret_cast<const float4*>(vp + 8);
            const float4 vd = *reinterpret_cast<const float4*>(vp + 12);
            const unsigned char* ps = rp + 1024 * s;
#pragma unroll
            for (int r = 0; r < 8; r++) {
                uint4 kk = *reinterpret_cast<const uint4*>(ps + (size_t)r * NN);
                float f[16];
                cvt16(kk, f);
                float a = acc[r];
                a = fmaf(f[0],  va.x, a); a = fmaf(f[1],  va.y, a);
                a = fmaf(f[2],  va.z, a); a = fmaf(f[3],  va.w, a);
                a = fmaf(f[4],  vb.x, a); a = fmaf(f[5],  vb.y, a);
                a = fmaf(f[6],  vb.z, a); a = fmaf(f[7],  vb.w, a);
                a = fmaf(f[8],  vc.x, a); a = fmaf(f[9],  vc.y, a);
                a = fmaf(f[10], vc.z, a); a = fmaf(f[11], vc.w, a);
                a = fmaf(f[12], vd.x, a); a = fmaf(f[13], vd.y, a);
                a = fmaf(f[14], vd.z, a); a = fmaf(f[15], vd.w, a);
                acc[r] = a;
            }
        }
#pragma unroll
        for (int r = 0; r < 8; r++) {
            float pp = acc[r];
            for (int off = 32; off > 0; off >>= 1) pp += __shfl_down(pp, off);
            if (lane == 0) u_arr[rbase + r] = kMass / (pp * kInvSc + kStab);
        }
    } else {
        const int zz = z - 1;
        const unsigned char* K = K8 + (size_t)z * NN * NN;
        const float* xraw = small + OFF_SV + p * 2 * NN + zz * NN;
        float* yout = small + OFF_SU + p * 2 * NN + zz * NN;
        float* zbuf = small + OFF_SU + q * 2 * NN + zz * NN;
        symv_tile(K, xraw, yout, zbuf, smem, blockIdx.x);
    }
}

// -------------------------------- w[z] = sum u_i K_ij v_j cost_ij, cost = -eps*ln(K)
__global__ __launch_bounds__(256) void sk_wsum(const unsigned char* __restrict__ K8,
                                               const float* __restrict__ small,
                                               double* __restrict__ acc_out) {
    __shared__ float vs[10240];
    __shared__ double wred[4];
    const int t = threadIdx.x;
    const int z = blockIdx.z;
    const unsigned char* K = K8 + (size_t)z * NN * NN;
    const float* SV1 = small + OFF_SV + 2 * NN + (z - 1) * NN;  // valid for z>=1
    const float* SU1 = small + OFF_SU + 2 * NN + (z - 1) * NN;

#pragma unroll
    for (int qq = 0; qq < 8; qq++) {
        const int j = 4 * t + 1024 * qq;
        float4 g;
        if (z == 0) {
            g = *reinterpret_cast<const float4*>(small + OFF_VBUF + j);
        } else {
            float4 r = *reinterpret_cast<const float4*>(SV1 + j);
            g.x = xform(r.x); g.y = xform(r.y); g.z = xform(r.z); g.w = xform(r.w);
        }
        *reinterpret_cast<float4*>(&vs[SIDX(j)]) = g;
    }
    __syncthreads();

    const int lane = t & 63, w = t >> 6;
    const int rbase = blockIdx.x * 32 + 8 * w;
    float pr[8] = {};
    const unsigned char* rp = K + (size_t)rbase * NN + 16 * lane;
    for (int s = 0; s < 8; s++) {
        const float* vp = &vs[20 * lane + 1280 * s];
        float vv[16];
#pragma unroll
        for (int g = 0; g < 4; g++) {
            float4 v4 = *reinterpret_cast<const float4*>(vp + 4 * g);
            vv[4 * g] = v4.x; vv[4 * g + 1] = v4.y; vv[4 * g + 2] = v4.z; vv[4 * g + 3] = v4.w;
        }
        const unsigned char* ps = rp + 1024 * s;
#pragma unroll
        for (int r = 0; r < 8; r++) {
            uint4 kk = *reinterpret_cast<const uint4*>(ps + (size_t)r * NN);
            float f[16];
            cvt16(kk, f);
            float a = pr[r];
#pragma unroll
            for (int j = 0; j < 16; j++)
                a = fmaf(f[j] * vv[j], __logf(fmaxf(f[j], 1e-30f) * kInvSc), a);
            pr[r] = a;
        }
    }
    double lacc = 0.0;
#pragma unroll
    for (int r = 0; r < 8; r++) {
        const int gi = rbase + r;
        float ur;
        if (z == 0) ur = small[OFF_U + gi];
        else        ur = kMass / (SU1[gi] * kInvSc + kStab);
        lacc += (double)(ur * pr[r]);
    }
    lacc *= (double)kInvSc;
    for (int off = 32; off > 0; off >>= 1) lacc += __shfl_down(lacc, off);
    if (lane == 0) wred[w] = lacc;
    __syncthreads();
    if (t == 0) {
        double total = -(double)kEps * (wred[0] + wred[1] + wred[2] + wred[3]);
        atomicAdd(&acc_out[z], total);
    }
}

// ------------------------------------------------- combine
__global__ void sk_combine(const double* __restrict__ acc, float* __restrict__ out) {
    if (threadIdx.x == 0)
        out[0] = (float)((acc[0] - 0.5 * acc[1] - 0.5 * acc[2]) / 8192.0);
}

extern "C" void kernel_launch(void* const* d_in, const int* in_sizes, int n_in,
                              void* d_out, int out_size, void* d_ws, size_t ws_size,
                              hipStream_t stream) {
    const float* src = (const float*)d_in[0];
    const float* tgt = (const float*)d_in[1];
    float* out = (float*)d_out;
    char* ws = (char*)d_ws;

    unsigned char* K8 = (unsigned char*)ws;
    float* small = (float*)(ws + 3ull * NN * NN);
    double* wacc = (double*)(small + 12 * NN);

    sk_init<<<384, 256, 0, stream>>>(small, wacc);
    sk_build_k<<<dim3(128, 128, 3), 256, 0, stream>>>(src, tgt, K8);
    for (int it = 0; it < 100; it++) {
        sk_phase1<<<dim3(528, 1, 3), 256, 0, stream>>>(K8, small, it);
        sk_phase2<<<dim3(528, 1, 3), 256, 0, stream>>>(K8, small, it);
    }
    sk_wsum<<<dim3(256, 1, 3), 256, 0, stream>>>(K8, small, wacc);
    sk_combine<<<1, 64, 0, stream>>>(wacc, out);
}